// Round 1
// baseline (4767.106 us; speedup 1.0000x reference)
//
#include <hip/hip_runtime.h>
#include <math.h>

#define N_NODES 10000
#define N_EDGES 100000
#define N_GRAPH 64
#define CDIM 128
#define HCDIM 256
#define C3DIM 384
#define TEH 16   // edge-heads per block in edge kernel

// ---------------- generic GEMM: Y[M,N] = A[M,K] @ W[K,N] (+ bias) (+ silu) ----
template<int ACT>
__global__ __launch_bounds__(256) void gemm_kernel(
    const float* __restrict__ A, const float* __restrict__ W,
    const float* __restrict__ bias, float* __restrict__ Y,
    int M, int K, int N) {
  __shared__ float As[16][68];  // As[k][m], stride 68 avoids write conflicts
  __shared__ float Bs[16][65];
  const int tid = threadIdx.x;
  const int bm = blockIdx.y * 64, bn = blockIdx.x * 64;
  const int tx = tid & 15, ty = tid >> 4;
  float acc[4][4] = {};
  for (int k0 = 0; k0 < K; k0 += 16) {
#pragma unroll
    for (int i = 0; i < 4; ++i) {
      int l = tid + i * 256;
      int kk = l & 15, m = l >> 4;
      int gm = bm + m, gk = k0 + kk;
      As[kk][m] = (gm < M && gk < K) ? A[(size_t)gm * K + gk] : 0.f;
    }
#pragma unroll
    for (int i = 0; i < 4; ++i) {
      int l = tid + i * 256;
      int n = l & 63, kk = l >> 6;
      int gk = k0 + kk, gn = bn + n;
      Bs[kk][n] = (gk < K && gn < N) ? W[(size_t)gk * N + gn] : 0.f;
    }
    __syncthreads();
#pragma unroll
    for (int kk = 0; kk < 16; ++kk) {
      float a[4], b[4];
#pragma unroll
      for (int i = 0; i < 4; ++i) a[i] = As[kk][ty * 4 + i];
#pragma unroll
      for (int j = 0; j < 4; ++j) b[j] = Bs[kk][tx * 4 + j];
#pragma unroll
      for (int i = 0; i < 4; ++i)
#pragma unroll
        for (int j = 0; j < 4; ++j) acc[i][j] += a[i] * b[j];
    }
    __syncthreads();
  }
#pragma unroll
  for (int i = 0; i < 4; ++i) {
    int gm = bm + ty * 4 + i;
    if (gm >= M) continue;
#pragma unroll
    for (int j = 0; j < 4; ++j) {
      int gn = bn + tx * 4 + j;
      if (gn >= N) continue;
      float val = acc[i][j] + (bias ? bias[gn] : 0.f);
      if (ACT == 1) val = val / (1.f + expf(-val));  // silu
      Y[(size_t)gm * N + gn] = val;
    }
  }
}

// ---------------- fused per-edge kernel -------------------------------------
// For each edge-head: build kcat/mcat, alpha = qcat*kcat*scale, gate =
// sigmoid(LN_384(alpha)), t = (mcat@Wmu + bmu)*gate, m = LN_128(t@Wm + bm),
// atomic scatter-add into agg[dst].
__global__ __launch_bounds__(256) void edge_kernel(
    const float* __restrict__ q, const float* __restrict__ k,
    const float* __restrict__ v, const float* __restrict__ ea,
    const int* __restrict__ ei,  // [2,E] row0=src, row1=dst
    const float* __restrict__ Wmu, const float* __restrict__ bmu,
    const float* __restrict__ lag, const float* __restrict__ lab,
    const float* __restrict__ Wm, const float* __restrict__ bm,
    const float* __restrict__ lmg, const float* __restrict__ lmb,
    float* __restrict__ agg, int E) {
  __shared__ float smcat[TEH][C3DIM];
  __shared__ float sgate[TEH][C3DIM];
  __shared__ float sred[8];
  __shared__ float sstat[2];
  const int tid = threadIdx.x;
  const int ehbase = blockIdx.x * TEH;
  const float scale = 0.051031036307982884f;  // 1/sqrt(384)

  // ---- Phase A: gather + alpha + LN + sigmoid gate (per row, whole block) ----
  for (int r = 0; r < TEH; ++r) {
    int eh = ehbase + r;
    int e = eh >> 1, h = eh & 1;
    int srcn = ei[e], dstn = ei[E + e];
    int db = dstn * HCDIM + h * CDIM;
    int sb = srcn * HCDIM + h * CDIM;
    int eb = e * HCDIM + h * CDIM;
    float s = 0.f, s2 = 0.f;
    for (int f = tid; f < C3DIM; f += 256) {
      float kv, mv;
      if (f < 128)      { kv = k[db + f];        mv = v[db + f]; }
      else if (f < 256) { kv = k[sb + f - 128];  mv = v[sb + f - 128]; }
      else              { float t = ea[eb + f - 256]; kv = t; mv = t; }
      float al = q[db + (f & 127)] * kv * scale;
      smcat[r][f] = mv;
      sgate[r][f] = al;
      s += al; s2 += al * al;
    }
#pragma unroll
    for (int off = 32; off > 0; off >>= 1) {
      s += __shfl_down(s, off); s2 += __shfl_down(s2, off);
    }
    if ((tid & 63) == 0) { sred[tid >> 6] = s; sred[4 + (tid >> 6)] = s2; }
    __syncthreads();
    if (tid == 0) {
      float ts = sred[0] + sred[1] + sred[2] + sred[3];
      float t2 = sred[4] + sred[5] + sred[6] + sred[7];
      float mean = ts * (1.f / C3DIM);
      float var = t2 * (1.f / C3DIM) - mean * mean;
      sstat[0] = mean; sstat[1] = rsqrtf(var + 1e-5f);
    }
    __syncthreads();
    float mean = sstat[0], rstd = sstat[1];
    for (int f = tid; f < C3DIM; f += 256) {
      float z = (sgate[r][f] - mean) * rstd * lag[f] + lab[f];
      sgate[r][f] = 1.f / (1.f + expf(-z));
    }
    __syncthreads();
  }

  // ---- Phase B: t[r][g] = mcat[r]·Wmu[:,g] + bmu[g]; gated, back into smcat --
  const int gc = tid & 127, half = tid >> 7, r0 = half * 8;
  float acc[8][3];
#pragma unroll
  for (int rr = 0; rr < 8; ++rr) { acc[rr][0] = acc[rr][1] = acc[rr][2] = 0.f; }
  for (int f = 0; f < C3DIM; f += 4) {
    float w[4][3];
#pragma unroll
    for (int u = 0; u < 4; ++u) {
      const float* wrow = Wmu + (size_t)(f + u) * C3DIM;
      w[u][0] = wrow[gc]; w[u][1] = wrow[gc + 128]; w[u][2] = wrow[gc + 256];
    }
#pragma unroll
    for (int rr = 0; rr < 8; ++rr) {
      float a0 = smcat[r0 + rr][f],     a1 = smcat[r0 + rr][f + 1];
      float a2 = smcat[r0 + rr][f + 2], a3 = smcat[r0 + rr][f + 3];
      acc[rr][0] += a0 * w[0][0] + a1 * w[1][0] + a2 * w[2][0] + a3 * w[3][0];
      acc[rr][1] += a0 * w[0][1] + a1 * w[1][1] + a2 * w[2][1] + a3 * w[3][1];
      acc[rr][2] += a0 * w[0][2] + a1 * w[1][2] + a2 * w[2][2] + a3 * w[3][2];
    }
  }
  __syncthreads();
  {
    float b0 = bmu[gc], b1 = bmu[gc + 128], b2 = bmu[gc + 256];
#pragma unroll
    for (int rr = 0; rr < 8; ++rr) {
      int r = r0 + rr;
      smcat[r][gc]       = (acc[rr][0] + b0) * sgate[r][gc];
      smcat[r][gc + 128] = (acc[rr][1] + b1) * sgate[r][gc + 128];
      smcat[r][gc + 256] = (acc[rr][2] + b2) * sgate[r][gc + 256];
    }
  }
  __syncthreads();

  // ---- Phase C: m[r][c] = t_gated[r]·Wm[:,c] + bm[c]; LN_128; scatter-add ---
  float acc2[8] = {};
  for (int g = 0; g < C3DIM; g += 4) {
    float w0 = Wm[(size_t)g * CDIM + gc];
    float w1 = Wm[(size_t)(g + 1) * CDIM + gc];
    float w2 = Wm[(size_t)(g + 2) * CDIM + gc];
    float w3 = Wm[(size_t)(g + 3) * CDIM + gc];
#pragma unroll
    for (int rr = 0; rr < 8; ++rr) {
      acc2[rr] += smcat[r0 + rr][g] * w0 + smcat[r0 + rr][g + 1] * w1 +
                  smcat[r0 + rr][g + 2] * w2 + smcat[r0 + rr][g + 3] * w3;
    }
  }
  __syncthreads();  // done reading sgate in phase B epilogue; safe to overwrite
  {
    float bb = bm[gc];
#pragma unroll
    for (int rr = 0; rr < 8; ++rr) sgate[r0 + rr][gc] = acc2[rr] + bb;
  }
  __syncthreads();
  const int wave = tid >> 6, lane = tid & 63;
  for (int rw = wave; rw < TEH; rw += 4) {
    float v0 = sgate[rw][lane], v1 = sgate[rw][lane + 64];
    float s = v0 + v1, s2 = v0 * v0 + v1 * v1;
#pragma unroll
    for (int off = 32; off > 0; off >>= 1) {
      s += __shfl_down(s, off); s2 += __shfl_down(s2, off);
    }
    s = __shfl(s, 0); s2 = __shfl(s2, 0);
    float mean = s * (1.f / CDIM);
    float rstd = rsqrtf(s2 * (1.f / CDIM) - mean * mean + 1e-5f);
    int eh = ehbase + rw;
    int e = eh >> 1, h = eh & 1;
    int dstn = ei[E + e];
    float o0 = (v0 - mean) * rstd * lmg[lane] + lmb[lane];
    float o1 = (v1 - mean) * rstd * lmg[lane + 64] + lmb[lane + 64];
    atomicAdd(&agg[dstn * HCDIM + h * CDIM + lane], o0);
    atomicAdd(&agg[dstn * HCDIM + h * CDIM + lane + 64], o1);
  }
}

// ---------------- BN statistics: one block per channel ----------------------
__global__ __launch_bounds__(256) void bn_stats_kernel(
    const float* __restrict__ o, float* __restrict__ mu, float* __restrict__ rstd) {
  int c = blockIdx.x, tid = threadIdx.x;
  float s = 0.f, s2 = 0.f;
  for (int r = tid; r < N_NODES; r += 256) {
    float x = o[(size_t)r * CDIM + c];
    s += x; s2 += x * x;
  }
  __shared__ float red[8];
#pragma unroll
  for (int off = 32; off > 0; off >>= 1) {
    s += __shfl_down(s, off); s2 += __shfl_down(s2, off);
  }
  if ((tid & 63) == 0) { red[tid >> 6] = s; red[4 + (tid >> 6)] = s2; }
  __syncthreads();
  if (tid == 0) {
    float ts = red[0] + red[1] + red[2] + red[3];
    float t2 = red[4] + red[5] + red[6] + red[7];
    float m = ts * (1.f / N_NODES);
    float var = t2 * (1.f / N_NODES) - m * m;
    mu[c] = m;
    rstd[c] = rsqrtf(var + 1e-5f);
  }
}

// ---------------- fused BN + SiLU + root skip -------------------------------
__global__ void bn_silu_skip_kernel(
    const float* __restrict__ o, const float* __restrict__ skip,
    const float* __restrict__ mu, const float* __restrict__ rstd,
    const float* __restrict__ g, const float* __restrict__ b,
    float* __restrict__ nf) {
  int idx = blockIdx.x * blockDim.x + threadIdx.x;
  if (idx >= N_NODES * CDIM) return;
  int c = idx & (CDIM - 1);
  float x = (o[idx] - mu[c]) * rstd[c] * g[c] + b[c];
  float sig = 1.f / (1.f + expf(-x));
  nf[idx] = x * sig + skip[idx];
}

// ---------------- mean pool (atomic) ----------------------------------------
__global__ void pool_kernel(const float* __restrict__ nf, const int* __restrict__ batch,
                            float* __restrict__ psum, float* __restrict__ cnt) {
  int idx = blockIdx.x * blockDim.x + threadIdx.x;
  if (idx >= N_NODES * CDIM) return;
  int n = idx >> 7, c = idx & 127;
  int b = batch[n];
  atomicAdd(&psum[b * CDIM + c], nf[idx]);
  if (c == 0) atomicAdd(&cnt[b], 1.f);
}

__global__ void feats_kernel(const float* __restrict__ psum, const float* __restrict__ cnt,
                             const float* __restrict__ pge, const float* __restrict__ cse,
                             float* __restrict__ feats) {
  int idx = blockIdx.x * blockDim.x + threadIdx.x;
  if (idx >= N_GRAPH * 167) return;
  int b = idx / 167, j = idx - b * 167;
  float val;
  if (j < 128)      val = psum[b * CDIM + j] / fmaxf(cnt[b], 1.f);
  else if (j < 160) val = pge[b * 32 + (j - 128)];
  else              val = cse[b * 7 + (j - 160)];
  feats[idx] = val;
}

__global__ __launch_bounds__(256) void out_kernel(
    const float* __restrict__ h, const float* __restrict__ ow,
    const float* __restrict__ ob, float* __restrict__ out) {
  int b = blockIdx.x, tid = threadIdx.x;
  float s = h[b * 512 + tid] * ow[tid] + h[b * 512 + tid + 256] * ow[tid + 256];
  __shared__ float red[4];
#pragma unroll
  for (int off = 32; off > 0; off >>= 1) s += __shfl_down(s, off);
  if ((tid & 63) == 0) red[tid >> 6] = s;
  __syncthreads();
  if (tid == 0) out[b] = red[0] + red[1] + red[2] + red[3] + ob[0];
}

// ---------------- launch -----------------------------------------------------
extern "C" void kernel_launch(void* const* d_in, const int* in_sizes, int n_in,
                              void* d_out, int out_size, void* d_ws, size_t ws_size,
                              hipStream_t stream) {
  const float* x         = (const float*)d_in[0];
  const float* edge_attr = (const float*)d_in[1];
  const float* pge       = (const float*)d_in[2];
  const float* cse       = (const float*)d_in[3];
  const int*   ei        = (const int*)d_in[4];
  const int*   batch     = (const int*)d_in[5];
  const float* atom_W    = (const float*)d_in[6];
  const float* atom_b    = (const float*)d_in[7];
  const float* edge_W    = (const float*)d_in[8];
  const float* edge_b    = (const float*)d_in[9];
  const float* Wq        = (const float*)d_in[10];
  const float* bq        = (const float*)d_in[11];
  const float* Wk        = (const float*)d_in[12];
  const float* bk        = (const float*)d_in[13];
  const float* Wv        = (const float*)d_in[14];
  const float* bv        = (const float*)d_in[15];
  const float* We        = (const float*)d_in[16];
  const float* Wmu       = (const float*)d_in[17];
  const float* bmu       = (const float*)d_in[18];
  const float* Wm        = (const float*)d_in[19];
  const float* bm        = (const float*)d_in[20];
  const float* ln_m_g    = (const float*)d_in[21];
  const float* ln_m_b    = (const float*)d_in[22];
  const float* ln_a_g    = (const float*)d_in[23];
  const float* ln_a_b    = (const float*)d_in[24];
  const float* Wc        = (const float*)d_in[25];
  const float* bc        = (const float*)d_in[26];
  const float* bn_g      = (const float*)d_in[27];
  const float* bn_b      = (const float*)d_in[28];
  const float* Wskip     = (const float*)d_in[29];
  const float* bskip     = (const float*)d_in[30];
  const float* fc_W      = (const float*)d_in[31];
  const float* fc_b      = (const float*)d_in[32];
  const float* out_W     = (const float*)d_in[33];
  const float* out_b     = (const float*)d_in[34];

  float* ws = (float*)d_ws;
  size_t off = 0;
  float* nf    = ws + off; off += (size_t)N_NODES * CDIM;
  float* ef    = ws + off; off += (size_t)N_EDGES * CDIM;
  float* q     = ws + off; off += (size_t)N_NODES * HCDIM;
  float* k     = ws + off; off += (size_t)N_NODES * HCDIM;
  float* v     = ws + off; off += (size_t)N_NODES * HCDIM;
  float* ea    = ws + off; off += (size_t)N_EDGES * HCDIM;
  float* agg   = ws + off; off += (size_t)N_NODES * HCDIM;
  float* o     = ws + off; off += (size_t)N_NODES * CDIM;
  float* skip  = ws + off; off += (size_t)N_NODES * CDIM;
  float* mu    = ws + off; off += CDIM;
  float* rstd  = ws + off; off += CDIM;
  float* psum  = ws + off; off += (size_t)N_GRAPH * CDIM;
  float* cnt   = ws + off; off += N_GRAPH;
  float* feats = ws + off; off += (size_t)N_GRAPH * 167;
  float* h     = ws + off; off += (size_t)N_GRAPH * 512;

  auto gemm = [&](const float* A, const float* W, const float* bias, float* Y,
                  int M, int K, int Nn, int act) {
    dim3 grid((Nn + 63) / 64, (M + 63) / 64);
    if (act) gemm_kernel<1><<<grid, 256, 0, stream>>>(A, W, bias, Y, M, K, Nn);
    else     gemm_kernel<0><<<grid, 256, 0, stream>>>(A, W, bias, Y, M, K, Nn);
  };

  gemm(x, atom_W, atom_b, nf, N_NODES, 92, CDIM, 0);
  gemm(edge_attr, edge_W, edge_b, ef, N_EDGES, 50, CDIM, 0);

  for (int i = 0; i < 2; ++i) {
    gemm(nf, Wq + (size_t)i * CDIM * HCDIM, bq + i * HCDIM, q, N_NODES, CDIM, HCDIM, 0);
    gemm(nf, Wk + (size_t)i * CDIM * HCDIM, bk + i * HCDIM, k, N_NODES, CDIM, HCDIM, 0);
    gemm(nf, Wv + (size_t)i * CDIM * HCDIM, bv + i * HCDIM, v, N_NODES, CDIM, HCDIM, 0);
    gemm(ef, We + (size_t)i * CDIM * HCDIM, nullptr, ea, N_EDGES, CDIM, HCDIM, 0);
    hipMemsetAsync(agg, 0, (size_t)N_NODES * HCDIM * sizeof(float), stream);
    edge_kernel<<<dim3(N_EDGES * 2 / TEH), dim3(256), 0, stream>>>(
        q, k, v, ea, ei,
        Wmu + (size_t)i * C3DIM * C3DIM, bmu + i * C3DIM,
        ln_a_g + i * C3DIM, ln_a_b + i * C3DIM,
        Wm + (size_t)i * C3DIM * CDIM, bm + i * CDIM,
        ln_m_g + i * CDIM, ln_m_b + i * CDIM, agg, N_EDGES);
    gemm(agg, Wc + (size_t)i * HCDIM * CDIM, bc + i * CDIM, o, N_NODES, HCDIM, CDIM, 0);
    bn_stats_kernel<<<dim3(CDIM), dim3(256), 0, stream>>>(o, mu, rstd);
    gemm(nf, Wskip + (size_t)i * CDIM * CDIM, bskip + i * CDIM, skip, N_NODES, CDIM, CDIM, 0);
    bn_silu_skip_kernel<<<dim3((N_NODES * CDIM + 255) / 256), dim3(256), 0, stream>>>(
        o, skip, mu, rstd, bn_g + i * CDIM, bn_b + i * CDIM, nf);
  }

  hipMemsetAsync(psum, 0, (size_t)(N_GRAPH * CDIM + N_GRAPH) * sizeof(float), stream);
  pool_kernel<<<dim3((N_NODES * CDIM + 255) / 256), dim3(256), 0, stream>>>(nf, batch, psum, cnt);
  feats_kernel<<<dim3((N_GRAPH * 167 + 255) / 256), dim3(256), 0, stream>>>(psum, cnt, pge, cse, feats);
  gemm(feats, fc_W, fc_b, h, N_GRAPH, 167, 512, 1);
  out_kernel<<<dim3(N_GRAPH), dim3(256), 0, stream>>>(h, out_W, out_b, (float*)d_out);
}

// Round 2
// 2944.007 us; speedup vs baseline: 1.6193x; 1.6193x over previous
//
#include <hip/hip_runtime.h>
#include <math.h>

#define N_NODES 10000
#define N_EDGES 100000
#define N_GRAPH 64
#define CDIM 128
#define HCDIM 256
#define C3DIM 384
#define EPB 8    // edges per block in edge kernel (16 edge-heads)

// ---------------- generic GEMM: Y[M,N] = A[M,K] @ W[K,N] (+ bias) (+ silu) ----
template<int ACT>
__global__ __launch_bounds__(256) void gemm_kernel(
    const float* __restrict__ A, const float* __restrict__ W,
    const float* __restrict__ bias, float* __restrict__ Y,
    int M, int K, int N) {
  __shared__ float As[16][68];
  __shared__ float Bs[16][65];
  const int tid = threadIdx.x;
  const int bm = blockIdx.y * 64, bn = blockIdx.x * 64;
  const int tx = tid & 15, ty = tid >> 4;
  float acc[4][4] = {};
  for (int k0 = 0; k0 < K; k0 += 16) {
#pragma unroll
    for (int i = 0; i < 4; ++i) {
      int l = tid + i * 256;
      int kk = l & 15, m = l >> 4;
      int gm = bm + m, gk = k0 + kk;
      As[kk][m] = (gm < M && gk < K) ? A[(size_t)gm * K + gk] : 0.f;
    }
#pragma unroll
    for (int i = 0; i < 4; ++i) {
      int l = tid + i * 256;
      int n = l & 63, kk = l >> 6;
      int gk = k0 + kk, gn = bn + n;
      Bs[kk][n] = (gk < K && gn < N) ? W[(size_t)gk * N + gn] : 0.f;
    }
    __syncthreads();
#pragma unroll
    for (int kk = 0; kk < 16; ++kk) {
      float a[4], b[4];
#pragma unroll
      for (int i = 0; i < 4; ++i) a[i] = As[kk][ty * 4 + i];
#pragma unroll
      for (int j = 0; j < 4; ++j) b[j] = Bs[kk][tx * 4 + j];
#pragma unroll
      for (int i = 0; i < 4; ++i)
#pragma unroll
        for (int j = 0; j < 4; ++j) acc[i][j] += a[i] * b[j];
    }
    __syncthreads();
  }
#pragma unroll
  for (int i = 0; i < 4; ++i) {
    int gm = bm + ty * 4 + i;
    if (gm >= M) continue;
#pragma unroll
    for (int j = 0; j < 4; ++j) {
      int gn = bn + tx * 4 + j;
      if (gn >= N) continue;
      float val = acc[i][j] + (bias ? bias[gn] : 0.f);
      if (ACT == 1) val = val / (1.f + expf(-val));
      Y[(size_t)gm * N + gn] = val;
    }
  }
}

// ---------------- weight composition ----------------------------------------
// z<4:  WP12[c][part*768 + h*384 + g] = sum_d Wv[c][h*128+d] * Wmu[part*128+d][g]
// z>=4: WPe [c][h*384 + g]            = sum_f We[c][h*128+f] * Wmu[256+f][g]
__global__ __launch_bounds__(256) void compose_kernel(
    const float* __restrict__ Wv, const float* __restrict__ We,
    const float* __restrict__ Wmu, float* __restrict__ WP12,
    float* __restrict__ WPe) {
  const int z = blockIdx.z;
  const float* Ap; const float* Bp; float* Cp; int ldc;
  if (z < 4) {
    int part = z >> 1, h = z & 1;
    Ap = Wv + h * 128; Bp = Wmu + part * 128 * 384;
    Cp = WP12 + part * 768 + h * 384; ldc = 1536;
  } else {
    int h = z - 4;
    Ap = We + h * 128; Bp = Wmu + 256 * 384;
    Cp = WPe + h * 384; ldc = 768;
  }
  __shared__ float As[16][68];
  __shared__ float Bs[16][65];
  const int tid = threadIdx.x;
  const int bm = blockIdx.y * 64, bn = blockIdx.x * 64;
  const int tx = tid & 15, ty = tid >> 4;
  float acc[4][4] = {};
  for (int k0 = 0; k0 < 128; k0 += 16) {
#pragma unroll
    for (int i = 0; i < 4; ++i) {
      int l = tid + i * 256;
      int kk = l & 15, m = l >> 4;
      As[kk][m] = Ap[(size_t)(bm + m) * 256 + k0 + kk];
    }
#pragma unroll
    for (int i = 0; i < 4; ++i) {
      int l = tid + i * 256;
      int n = l & 63, kk = l >> 6;
      Bs[kk][n] = Bp[(size_t)(k0 + kk) * 384 + bn + n];
    }
    __syncthreads();
#pragma unroll
    for (int kk = 0; kk < 16; ++kk) {
      float a[4], b[4];
#pragma unroll
      for (int i = 0; i < 4; ++i) a[i] = As[kk][ty * 4 + i];
#pragma unroll
      for (int j = 0; j < 4; ++j) b[j] = Bs[kk][tx * 4 + j];
#pragma unroll
      for (int i = 0; i < 4; ++i)
#pragma unroll
        for (int j = 0; j < 4; ++j) acc[i][j] += a[i] * b[j];
    }
    __syncthreads();
  }
#pragma unroll
  for (int i = 0; i < 4; ++i)
#pragma unroll
    for (int j = 0; j < 4; ++j)
      Cp[(size_t)(bm + ty * 4 + i) * ldc + bn + tx * 4 + j] = acc[i][j];
}

// cb[h*384+g] = bmu[g] + sum_d bv[h*128+d] * (Wmu[d][g] + Wmu[128+d][g])
__global__ void cb_kernel(const float* __restrict__ bmu, const float* __restrict__ bv,
                          const float* __restrict__ Wmu, float* __restrict__ cb) {
  int j = blockIdx.x * blockDim.x + threadIdx.x;
  if (j >= 768) return;
  int h = j / 384, g = j - h * 384;
  float s = bmu[g];
  for (int d = 0; d < 128; ++d)
    s += bv[h * 128 + d] * (Wmu[(size_t)d * 384 + g] + Wmu[(size_t)(128 + d) * 384 + g]);
  cb[j] = s;
}

// ---------------- fused per-edge kernel (decomposed) ------------------------
// Per block: 8 edges x 2 heads. row r = h*8 + e.
//  P2a: sea = ef @ We_h (in LDS, aliased into st[r][256..384))
//  PA : alpha -> LN384 -> sigmoid gate (width-16 shuffle reductions)
//  P4 : Pe = ef @ WPe; t = Pe + P1[dst] + P2[src] + cb; st = t * gate
//  PC : m = st @ Wm + bm; LN128; atomic scatter-add to agg[dst]
__global__ __launch_bounds__(256) void edge_kernel(
    const float* __restrict__ q, const float* __restrict__ k,
    const float* __restrict__ ef, const int* __restrict__ ei,
    const float* __restrict__ We_l, const float* __restrict__ WPe,
    const float* __restrict__ P12, const float* __restrict__ cb,
    const float* __restrict__ lag, const float* __restrict__ lab,
    const float* __restrict__ Wm_l, const float* __restrict__ bm_l,
    const float* __restrict__ lmg, const float* __restrict__ lmb,
    float* __restrict__ agg, int E) {
  __shared__ __align__(16) float sef[EPB][128];
  __shared__ __align__(16) float st[16][384];
  __shared__ __align__(16) float sgate[16][384];
  __shared__ int sid[EPB], did[EPB];
  const int tid = threadIdx.x;
  const int e0 = blockIdx.x * EPB;
  const float scale = 0.051031036307982884f;  // 1/sqrt(384)

  if (tid < EPB) { sid[tid] = ei[e0 + tid]; did[tid] = ei[E + e0 + tid]; }
#pragma unroll
  for (int i = 0; i < 4; ++i) {
    int l = tid + i * 256;
    int e = l >> 7, f = l & 127;
    sef[e][f] = ef[(size_t)(e0 + e) * 128 + f];
  }
  __syncthreads();

  // ---- Phase 2a: sea[r][c] = sum_k sef[e][k] * We[k][h*128+c] ----
  {
    const int c = tid & 127, h = tid >> 7;
    float acc[EPB] = {};
    for (int kk = 0; kk < 128; kk += 4) {
      float w0 = We_l[(size_t)kk * 256 + h * 128 + c];
      float w1 = We_l[(size_t)(kk + 1) * 256 + h * 128 + c];
      float w2 = We_l[(size_t)(kk + 2) * 256 + h * 128 + c];
      float w3 = We_l[(size_t)(kk + 3) * 256 + h * 128 + c];
#pragma unroll
      for (int e = 0; e < EPB; ++e) {
        float4 a = *(const float4*)&sef[e][kk];
        acc[e] += a.x * w0 + a.y * w1 + a.z * w2 + a.w * w3;
      }
    }
#pragma unroll
    for (int e = 0; e < EPB; ++e) st[h * EPB + e][256 + c] = acc[e];
  }
  __syncthreads();

  // ---- Phase A: gate = sigmoid(LN384(alpha)), 16 lanes per row ----
  {
    const int r = tid >> 4, l = tid & 15;
    const int h = r >> 3, e = r & 7;
    const int dstn = did[e], srcn = sid[e];
    const int qb = dstn * HCDIM + h * CDIM;
    const int ksb = srcn * HCDIM + h * CDIM;
    float qv[8], al[24];
    float s = 0.f, s2 = 0.f;
#pragma unroll
    for (int j = 0; j < 8; ++j) qv[j] = q[qb + l + 16 * j];
#pragma unroll
    for (int j = 0; j < 8; ++j) {
      float a = qv[j] * k[qb + l + 16 * j] * scale;
      al[j] = a; s += a; s2 += a * a;
    }
#pragma unroll
    for (int j = 0; j < 8; ++j) {
      float a = qv[j] * k[ksb + l + 16 * j] * scale;
      al[8 + j] = a; s += a; s2 += a * a;
    }
#pragma unroll
    for (int j = 0; j < 8; ++j) {
      float a = qv[j] * st[r][256 + l + 16 * j] * scale;
      al[16 + j] = a; s += a; s2 += a * a;
    }
#pragma unroll
    for (int m = 1; m < 16; m <<= 1) {
      s += __shfl_xor(s, m); s2 += __shfl_xor(s2, m);
    }
    float mean = s * (1.f / C3DIM);
    float rstd = rsqrtf(s2 * (1.f / C3DIM) - mean * mean + 1e-5f);
#pragma unroll
    for (int j = 0; j < 24; ++j) {
      int f = (j >> 3) * 128 + l + 16 * (j & 7);
      float z = (al[j] - mean) * rstd * lag[f] + lab[f];
      sgate[r][f] = 1.f / (1.f + expf(-z));
    }
  }
  __syncthreads();

  // ---- Phase 4: Pe + gathers -> st = t * gate ----
  {
    const int c = tid & 127, h = tid >> 7;
    float acc0[EPB] = {}, acc1[EPB] = {}, acc2[EPB] = {};
    for (int kk = 0; kk < 128; kk += 4) {
      float w[4][3];
#pragma unroll
      for (int u = 0; u < 4; ++u) {
        const float* wr = WPe + (size_t)(kk + u) * 768 + h * 384;
        w[u][0] = wr[c]; w[u][1] = wr[c + 128]; w[u][2] = wr[c + 256];
      }
#pragma unroll
      for (int e = 0; e < EPB; ++e) {
        float4 a = *(const float4*)&sef[e][kk];
        acc0[e] += a.x * w[0][0] + a.y * w[1][0] + a.z * w[2][0] + a.w * w[3][0];
        acc1[e] += a.x * w[0][1] + a.y * w[1][1] + a.z * w[2][1] + a.w * w[3][1];
        acc2[e] += a.x * w[0][2] + a.y * w[1][2] + a.z * w[2][2] + a.w * w[3][2];
      }
    }
    float cb0 = cb[h * 384 + c], cb1 = cb[h * 384 + c + 128], cb2 = cb[h * 384 + c + 256];
#pragma unroll
    for (int e = 0; e < EPB; ++e) {
      int r = h * EPB + e;
      const float* pd = P12 + (size_t)did[e] * 1536 + h * 384;
      const float* ps = P12 + (size_t)sid[e] * 1536 + 768 + h * 384;
      float t0 = acc0[e] + pd[c] + ps[c] + cb0;
      float t1 = acc1[e] + pd[c + 128] + ps[c + 128] + cb1;
      float t2 = acc2[e] + pd[c + 256] + ps[c + 256] + cb2;
      st[r][c]       = t0 * sgate[r][c];
      st[r][c + 128] = t1 * sgate[r][c + 128];
      st[r][c + 256] = t2 * sgate[r][c + 256];
    }
  }
  __syncthreads();

  // ---- Phase C: m = st @ Wm + bm ----
  {
    const int gc = tid & 127, half = tid >> 7;
    const int r0 = half * EPB;
    float acc[EPB] = {};
    for (int g = 0; g < 384; g += 4) {
      float w0 = Wm_l[(size_t)g * 128 + gc];
      float w1 = Wm_l[(size_t)(g + 1) * 128 + gc];
      float w2 = Wm_l[(size_t)(g + 2) * 128 + gc];
      float w3 = Wm_l[(size_t)(g + 3) * 128 + gc];
#pragma unroll
      for (int rr = 0; rr < EPB; ++rr) {
        float4 a = *(const float4*)&st[r0 + rr][g];
        acc[rr] += a.x * w0 + a.y * w1 + a.z * w2 + a.w * w3;
      }
    }
    float bb = bm_l[gc];
#pragma unroll
    for (int rr = 0; rr < EPB; ++rr) sgate[r0 + rr][gc] = acc[rr] + bb;
  }
  __syncthreads();

  // ---- LN128 + scatter ----
  {
    const int wave = tid >> 6, lane = tid & 63;
    for (int rw = wave; rw < 16; rw += 4) {
      float v0 = sgate[rw][lane], v1 = sgate[rw][lane + 64];
      float s = v0 + v1, s2 = v0 * v0 + v1 * v1;
#pragma unroll
      for (int off = 32; off > 0; off >>= 1) {
        s += __shfl_down(s, off); s2 += __shfl_down(s2, off);
      }
      s = __shfl(s, 0); s2 = __shfl(s2, 0);
      float mean = s * (1.f / CDIM);
      float rstd = rsqrtf(s2 * (1.f / CDIM) - mean * mean + 1e-5f);
      int h = rw >> 3, e = rw & 7;
      int dstn = did[e];
      float o0 = (v0 - mean) * rstd * lmg[lane] + lmb[lane];
      float o1 = (v1 - mean) * rstd * lmg[lane + 64] + lmb[lane + 64];
      atomicAdd(&agg[(size_t)dstn * HCDIM + h * CDIM + lane], o0);
      atomicAdd(&agg[(size_t)dstn * HCDIM + h * CDIM + lane + 64], o1);
    }
  }
}

// ---------------- BN statistics ---------------------------------------------
__global__ __launch_bounds__(256) void bn_stats_kernel(
    const float* __restrict__ o, float* __restrict__ mu, float* __restrict__ rstd) {
  int c = blockIdx.x, tid = threadIdx.x;
  float s = 0.f, s2 = 0.f;
  for (int r = tid; r < N_NODES; r += 256) {
    float x = o[(size_t)r * CDIM + c];
    s += x; s2 += x * x;
  }
  __shared__ float red[8];
#pragma unroll
  for (int off = 32; off > 0; off >>= 1) {
    s += __shfl_down(s, off); s2 += __shfl_down(s2, off);
  }
  if ((tid & 63) == 0) { red[tid >> 6] = s; red[4 + (tid >> 6)] = s2; }
  __syncthreads();
  if (tid == 0) {
    float ts = red[0] + red[1] + red[2] + red[3];
    float t2 = red[4] + red[5] + red[6] + red[7];
    float m = ts * (1.f / N_NODES);
    float var = t2 * (1.f / N_NODES) - m * m;
    mu[c] = m;
    rstd[c] = rsqrtf(var + 1e-5f);
  }
}

__global__ void bn_silu_skip_kernel(
    const float* __restrict__ o, const float* __restrict__ skip,
    const float* __restrict__ mu, const float* __restrict__ rstd,
    const float* __restrict__ g, const float* __restrict__ b,
    float* __restrict__ nf) {
  int idx = blockIdx.x * blockDim.x + threadIdx.x;
  if (idx >= N_NODES * CDIM) return;
  int c = idx & (CDIM - 1);
  float x = (o[idx] - mu[c]) * rstd[c] * g[c] + b[c];
  float sig = 1.f / (1.f + expf(-x));
  nf[idx] = x * sig + skip[idx];
}

__global__ void pool_kernel(const float* __restrict__ nf, const int* __restrict__ batch,
                            float* __restrict__ psum, float* __restrict__ cnt) {
  int idx = blockIdx.x * blockDim.x + threadIdx.x;
  if (idx >= N_NODES * CDIM) return;
  int n = idx >> 7, c = idx & 127;
  int b = batch[n];
  atomicAdd(&psum[b * CDIM + c], nf[idx]);
  if (c == 0) atomicAdd(&cnt[b], 1.f);
}

__global__ void feats_kernel(const float* __restrict__ psum, const float* __restrict__ cnt,
                             const float* __restrict__ pge, const float* __restrict__ cse,
                             float* __restrict__ feats) {
  int idx = blockIdx.x * blockDim.x + threadIdx.x;
  if (idx >= N_GRAPH * 167) return;
  int b = idx / 167, j = idx - b * 167;
  float val;
  if (j < 128)      val = psum[b * CDIM + j] / fmaxf(cnt[b], 1.f);
  else if (j < 160) val = pge[b * 32 + (j - 128)];
  else              val = cse[b * 7 + (j - 160)];
  feats[idx] = val;
}

__global__ __launch_bounds__(256) void out_kernel(
    const float* __restrict__ h, const float* __restrict__ ow,
    const float* __restrict__ ob, float* __restrict__ out) {
  int b = blockIdx.x, tid = threadIdx.x;
  float s = h[b * 512 + tid] * ow[tid] + h[b * 512 + tid + 256] * ow[tid + 256];
  __shared__ float red[4];
#pragma unroll
  for (int off = 32; off > 0; off >>= 1) s += __shfl_down(s, off);
  if ((tid & 63) == 0) red[tid >> 6] = s;
  __syncthreads();
  if (tid == 0) out[b] = red[0] + red[1] + red[2] + red[3] + ob[0];
}

// ---------------- launch -----------------------------------------------------
extern "C" void kernel_launch(void* const* d_in, const int* in_sizes, int n_in,
                              void* d_out, int out_size, void* d_ws, size_t ws_size,
                              hipStream_t stream) {
  const float* x         = (const float*)d_in[0];
  const float* edge_attr = (const float*)d_in[1];
  const float* pge       = (const float*)d_in[2];
  const float* cse       = (const float*)d_in[3];
  const int*   ei        = (const int*)d_in[4];
  const int*   batch     = (const int*)d_in[5];
  const float* atom_W    = (const float*)d_in[6];
  const float* atom_b    = (const float*)d_in[7];
  const float* edge_W    = (const float*)d_in[8];
  const float* edge_b    = (const float*)d_in[9];
  const float* Wq        = (const float*)d_in[10];
  const float* bq        = (const float*)d_in[11];
  const float* Wk        = (const float*)d_in[12];
  const float* bk        = (const float*)d_in[13];
  const float* Wv        = (const float*)d_in[14];
  const float* bv        = (const float*)d_in[15];
  const float* We        = (const float*)d_in[16];
  const float* Wmu       = (const float*)d_in[17];
  const float* bmu       = (const float*)d_in[18];
  const float* Wm        = (const float*)d_in[19];
  const float* bm        = (const float*)d_in[20];
  const float* ln_m_g    = (const float*)d_in[21];
  const float* ln_m_b    = (const float*)d_in[22];
  const float* ln_a_g    = (const float*)d_in[23];
  const float* ln_a_b    = (const float*)d_in[24];
  const float* Wc        = (const float*)d_in[25];
  const float* bc        = (const float*)d_in[26];
  const float* bn_g      = (const float*)d_in[27];
  const float* bn_b      = (const float*)d_in[28];
  const float* Wskip     = (const float*)d_in[29];
  const float* bskip     = (const float*)d_in[30];
  const float* fc_W      = (const float*)d_in[31];
  const float* fc_b      = (const float*)d_in[32];
  const float* out_W     = (const float*)d_in[33];
  const float* out_b     = (const float*)d_in[34];

  float* ws = (float*)d_ws;
  size_t off = 0;
  float* nf    = ws + off; off += (size_t)N_NODES * CDIM;
  float* ef    = ws + off; off += (size_t)N_EDGES * CDIM;
  float* q     = ws + off; off += (size_t)N_NODES * HCDIM;
  float* k     = ws + off; off += (size_t)N_NODES * HCDIM;
  float* P12   = ws + off; off += (size_t)N_NODES * 1536;
  float* agg   = ws + off; off += (size_t)N_NODES * HCDIM;
  float* o     = ws + off; off += (size_t)N_NODES * CDIM;
  float* skip  = ws + off; off += (size_t)N_NODES * CDIM;
  float* WP12  = ws + off; off += (size_t)128 * 1536;
  float* WPe   = ws + off; off += (size_t)128 * 768;
  float* cbv   = ws + off; off += 768;
  float* mu    = ws + off; off += CDIM;
  float* rstd  = ws + off; off += CDIM;
  float* psum  = ws + off; off += (size_t)N_GRAPH * CDIM;
  float* cnt   = ws + off; off += N_GRAPH;
  float* feats = ws + off; off += (size_t)N_GRAPH * 167;
  float* h     = ws + off; off += (size_t)N_GRAPH * 512;

  auto gemm = [&](const float* A, const float* W, const float* bias, float* Y,
                  int M, int K, int Nn, int act) {
    dim3 grid((Nn + 63) / 64, (M + 63) / 64);
    if (act) gemm_kernel<1><<<grid, 256, 0, stream>>>(A, W, bias, Y, M, K, Nn);
    else     gemm_kernel<0><<<grid, 256, 0, stream>>>(A, W, bias, Y, M, K, Nn);
  };

  gemm(x, atom_W, atom_b, nf, N_NODES, 92, CDIM, 0);
  gemm(edge_attr, edge_W, edge_b, ef, N_EDGES, 50, CDIM, 0);

  for (int i = 0; i < 2; ++i) {
    const float* Wv_i  = Wv + (size_t)i * CDIM * HCDIM;
    const float* We_i  = We + (size_t)i * CDIM * HCDIM;
    const float* Wmu_i = Wmu + (size_t)i * C3DIM * C3DIM;
    compose_kernel<<<dim3(6, 2, 6), 256, 0, stream>>>(Wv_i, We_i, Wmu_i, WP12, WPe);
    cb_kernel<<<dim3(3), dim3(256), 0, stream>>>(bmu + i * C3DIM, bv + i * HCDIM, Wmu_i, cbv);
    gemm(nf, Wq + (size_t)i * CDIM * HCDIM, bq + i * HCDIM, q, N_NODES, CDIM, HCDIM, 0);
    gemm(nf, Wk + (size_t)i * CDIM * HCDIM, bk + i * HCDIM, k, N_NODES, CDIM, HCDIM, 0);
    gemm(nf, WP12, nullptr, P12, N_NODES, CDIM, 1536, 0);
    hipMemsetAsync(agg, 0, (size_t)N_NODES * HCDIM * sizeof(float), stream);
    edge_kernel<<<dim3(N_EDGES / EPB), dim3(256), 0, stream>>>(
        q, k, ef, ei, We_i, WPe, P12, cbv,
        ln_a_g + i * C3DIM, ln_a_b + i * C3DIM,
        Wm + (size_t)i * C3DIM * CDIM, bm + i * CDIM,
        ln_m_g + i * CDIM, ln_m_b + i * CDIM, agg, N_EDGES);
    gemm(agg, Wc + (size_t)i * HCDIM * CDIM, bc + i * CDIM, o, N_NODES, HCDIM, CDIM, 0);
    bn_stats_kernel<<<dim3(CDIM), dim3(256), 0, stream>>>(o, mu, rstd);
    gemm(nf, Wskip + (size_t)i * CDIM * CDIM, bskip + i * CDIM, skip, N_NODES, CDIM, CDIM, 0);
    bn_silu_skip_kernel<<<dim3((N_NODES * CDIM + 255) / 256), dim3(256), 0, stream>>>(
        o, skip, mu, rstd, bn_g + i * CDIM, bn_b + i * CDIM, nf);
  }

  hipMemsetAsync(psum, 0, (size_t)(N_GRAPH * CDIM + N_GRAPH) * sizeof(float), stream);
  pool_kernel<<<dim3((N_NODES * CDIM + 255) / 256), dim3(256), 0, stream>>>(nf, batch, psum, cnt);
  feats_kernel<<<dim3((N_GRAPH * 167 + 255) / 256), dim3(256), 0, stream>>>(psum, cnt, pge, cse, feats);
  gemm(feats, fc_W, fc_b, h, N_GRAPH, 167, 512, 1);
  out_kernel<<<dim3(N_GRAPH), dim3(256), 0, stream>>>(h, out_W, out_b, (float*)d_out);
}

// Round 3
// 1711.765 us; speedup vs baseline: 2.7849x; 1.7199x over previous
//
#include <hip/hip_runtime.h>
#include <math.h>

#define N_NODES 10000
#define N_EDGES 100000
#define N_GRAPH 64
#define CDIM 128
#define HCDIM 256
#define C3DIM 384

typedef unsigned short u16;
typedef __attribute__((ext_vector_type(8))) short bf16x8;
typedef __attribute__((ext_vector_type(4))) float f32x4;

__device__ __forceinline__ u16 f2bf(float f) {
  union { float f; unsigned int u; } x; x.f = f;
  unsigned int u = x.u + 0x7fffu + ((x.u >> 16) & 1u);
  return (u16)(u >> 16);
}
__device__ __forceinline__ float bf2f(u16 h) {
  union { unsigned int u; float f; } x; x.u = ((unsigned int)h) << 16;
  return x.f;
}

// ---------------- generic fp32 GEMM: Y[M,N] = A[M,K] @ W[K,N] (+bias)(+silu) --
template<int ACT>
__global__ __launch_bounds__(256) void gemm_kernel(
    const float* __restrict__ A, const float* __restrict__ W,
    const float* __restrict__ bias, float* __restrict__ Y,
    int M, int K, int N) {
  __shared__ float As[16][68];
  __shared__ float Bs[16][65];
  const int tid = threadIdx.x;
  const int bm = blockIdx.y * 64, bn = blockIdx.x * 64;
  const int tx = tid & 15, ty = tid >> 4;
  float acc[4][4] = {};
  for (int k0 = 0; k0 < K; k0 += 16) {
#pragma unroll
    for (int i = 0; i < 4; ++i) {
      int l = tid + i * 256;
      int kk = l & 15, m = l >> 4;
      int gm = bm + m, gk = k0 + kk;
      As[kk][m] = (gm < M && gk < K) ? A[(size_t)gm * K + gk] : 0.f;
    }
#pragma unroll
    for (int i = 0; i < 4; ++i) {
      int l = tid + i * 256;
      int n = l & 63, kk = l >> 6;
      int gk = k0 + kk, gn = bn + n;
      Bs[kk][n] = (gk < K && gn < N) ? W[(size_t)gk * N + gn] : 0.f;
    }
    __syncthreads();
#pragma unroll
    for (int kk = 0; kk < 16; ++kk) {
      float a[4], b[4];
#pragma unroll
      for (int i = 0; i < 4; ++i) a[i] = As[kk][ty * 4 + i];
#pragma unroll
      for (int j = 0; j < 4; ++j) b[j] = Bs[kk][tx * 4 + j];
#pragma unroll
      for (int i = 0; i < 4; ++i)
#pragma unroll
        for (int j = 0; j < 4; ++j) acc[i][j] += a[i] * b[j];
    }
    __syncthreads();
  }
#pragma unroll
  for (int i = 0; i < 4; ++i) {
    int gm = bm + ty * 4 + i;
    if (gm >= M) continue;
#pragma unroll
    for (int j = 0; j < 4; ++j) {
      int gn = bn + tx * 4 + j;
      if (gn >= N) continue;
      float val = acc[i][j] + (bias ? bias[gn] : 0.f);
      if (ACT == 1) val = val / (1.f + expf(-val));
      Y[(size_t)gm * N + gn] = val;
    }
  }
}

// ---------------- weight composition (fp32) ----------------------------------
__global__ __launch_bounds__(256) void compose_kernel(
    const float* __restrict__ Wv, const float* __restrict__ We,
    const float* __restrict__ Wmu, float* __restrict__ WP12,
    float* __restrict__ WPe) {
  const int z = blockIdx.z;
  const float* Ap; const float* Bp; float* Cp; int ldc;
  if (z < 4) {
    int part = z >> 1, h = z & 1;
    Ap = Wv + h * 128; Bp = Wmu + part * 128 * 384;
    Cp = WP12 + part * 768 + h * 384; ldc = 1536;
  } else {
    int h = z - 4;
    Ap = We + h * 128; Bp = Wmu + 256 * 384;
    Cp = WPe + h * 384; ldc = 768;
  }
  __shared__ float As[16][68];
  __shared__ float Bs[16][65];
  const int tid = threadIdx.x;
  const int bm = blockIdx.y * 64, bn = blockIdx.x * 64;
  const int tx = tid & 15, ty = tid >> 4;
  float acc[4][4] = {};
  for (int k0 = 0; k0 < 128; k0 += 16) {
#pragma unroll
    for (int i = 0; i < 4; ++i) {
      int l = tid + i * 256;
      int kk = l & 15, m = l >> 4;
      As[kk][m] = Ap[(size_t)(bm + m) * 256 + k0 + kk];
    }
#pragma unroll
    for (int i = 0; i < 4; ++i) {
      int l = tid + i * 256;
      int n = l & 63, kk = l >> 6;
      Bs[kk][n] = Bp[(size_t)(k0 + kk) * 384 + bn + n];
    }
    __syncthreads();
#pragma unroll
    for (int kk = 0; kk < 16; ++kk) {
      float a[4], b[4];
#pragma unroll
      for (int i = 0; i < 4; ++i) a[i] = As[kk][ty * 4 + i];
#pragma unroll
      for (int j = 0; j < 4; ++j) b[j] = Bs[kk][tx * 4 + j];
#pragma unroll
      for (int i = 0; i < 4; ++i)
#pragma unroll
        for (int j = 0; j < 4; ++j) acc[i][j] += a[i] * b[j];
    }
    __syncthreads();
  }
#pragma unroll
  for (int i = 0; i < 4; ++i)
#pragma unroll
    for (int j = 0; j < 4; ++j)
      Cp[(size_t)(bm + ty * 4 + i) * ldc + bn + tx * 4 + j] = acc[i][j];
}

__global__ void cb_kernel(const float* __restrict__ bmu, const float* __restrict__ bv,
                          const float* __restrict__ Wmu, float* __restrict__ cb) {
  int j = blockIdx.x * blockDim.x + threadIdx.x;
  if (j >= 768) return;
  int h = j / 384, g = j - h * 384;
  float s = bmu[g];
  for (int d = 0; d < 128; ++d)
    s += bv[h * 128 + d] * (Wmu[(size_t)d * 384 + g] + Wmu[(size_t)(128 + d) * 384 + g]);
  cb[j] = s;
}

// ---------------- bf16 pack kernels -----------------------------------------
__global__ void pack_ef_kernel(const float* __restrict__ ef, u16* __restrict__ efb) {
  int idx = blockIdx.x * blockDim.x + threadIdx.x;
  if (idx < N_EDGES * 128) efb[idx] = f2bf(ef[idx]);
}

// WcT[col][k], col<256 -> We[k][col], else WPe[k][col-256]
__global__ void pack_wcombT_kernel(const float* __restrict__ We_l,
                                   const float* __restrict__ WPe,
                                   u16* __restrict__ WcT) {
  int idx = blockIdx.x * blockDim.x + threadIdx.x;
  if (idx >= 1024 * 128) return;
  int col = idx >> 7, kk = idx & 127;
  float v = (col < 256) ? We_l[(size_t)kk * 256 + col]
                        : WPe[(size_t)kk * 768 + (col - 256)];
  WcT[idx] = f2bf(v);
}

// WmT[n][k] = Wm[k][n]
__global__ void pack_wmT_kernel(const float* __restrict__ Wm_l, u16* __restrict__ WmT) {
  int idx = blockIdx.x * blockDim.x + threadIdx.x;
  if (idx >= 128 * 384) return;
  int n = idx / 384, kk = idx - n * 384;
  WmT[idx] = f2bf(Wm_l[(size_t)kk * 128 + n]);
}

// ---------------- fused per-edge kernel (MFMA) -------------------------------
// Block: 16 edges, 4 waves.
//  GEMM1 (MFMA): C1[16][1024] = ef_bf16 @ [We | WPe]  (sea cols 0..255, Pe 256..1023)
//  Then 2 sub-batches of 8 edges (rows r = h*8+e):
//   Phase A: alpha -> LN384 -> sigmoid gate (fp32)
//   Phase 4: t = Pe + P12[dst] + P12[src] + cb; *gate; -> A2p (bf16, A-frag order)
//   GEMM2 (MFMA): m[16][128] = A2 @ WmT; LN128; atomic scatter to agg[dst]
__global__ __launch_bounds__(256, 2) void edge_kernel(
    const float* __restrict__ q, const float* __restrict__ k,
    const u16* __restrict__ efb, const int* __restrict__ ei,
    const u16* __restrict__ WcT, const float* __restrict__ P12,
    const float* __restrict__ cb,
    const float* __restrict__ lag, const float* __restrict__ lab,
    const u16* __restrict__ WmT, const float* __restrict__ bm_l,
    const float* __restrict__ lmg, const float* __restrict__ lmb,
    float* __restrict__ agg, int E) {
  __shared__ __align__(16) u16 C1[16 * 1032];
  __shared__ __align__(16) u16 gate[16 * 392];
  __shared__ __align__(16) u16 A2p[12 * 512];   // aliased as C2 (float[16][132]) in GEMM2 epilogue
  __shared__ int sid16[16], did16[16];
  float* C2 = (float*)A2p;
  const int tid = threadIdx.x;
  const int e0 = blockIdx.x * 16;
  const int w = tid >> 6, l = tid & 63;
  const int lq = l >> 4, ln = l & 15;
  const float scale = 0.051031036307982884f;  // 1/sqrt(384)

  if (tid < 16) { sid16[tid] = ei[e0 + tid]; did16[tid] = ei[E + e0 + tid]; }

  // ---- GEMM1 ----
  {
    bf16x8 afr[4];
    const u16* ab = efb + (size_t)(e0 + ln) * 128 + lq * 8;
#pragma unroll
    for (int ks = 0; ks < 4; ++ks) afr[ks] = *(const bf16x8*)(ab + ks * 32);
    for (int nt = 0; nt < 16; ++nt) {
      int g = w * 16 + nt;
      const u16* bb = WcT + (size_t)(g * 16 + ln) * 128 + lq * 8;
      f32x4 acc = {0.f, 0.f, 0.f, 0.f};
#pragma unroll
      for (int ks = 0; ks < 4; ++ks)
        acc = __builtin_amdgcn_mfma_f32_16x16x32_bf16(
            afr[ks], *(const bf16x8*)(bb + ks * 32), acc, 0, 0, 0);
      int col = g * 16 + ln;
#pragma unroll
      for (int r = 0; r < 4; ++r) C1[(lq * 4 + r) * 1032 + col] = f2bf(acc[r]);
    }
  }
  __syncthreads();

  for (int s = 0; s < 2; ++s) {
    // ---- Phase A: gate ----
    {
      const int r = tid >> 4, lx = tid & 15;
      const int h = r >> 3, e = r & 7;
      const int edge = s * 8 + e;
      const int dstn = did16[edge], srcn = sid16[edge];
      const float* qp  = q + (size_t)dstn * HCDIM + h * CDIM + lx;
      const float* kdp = k + (size_t)dstn * HCDIM + h * CDIM + lx;
      const float* ksp = k + (size_t)srcn * HCDIM + h * CDIM + lx;
      const u16* sp = &C1[edge * 1032 + h * CDIM + lx];
      float qv[8], al[24], sacc = 0.f, s2acc = 0.f;
#pragma unroll
      for (int j = 0; j < 8; ++j) qv[j] = qp[16 * j];
#pragma unroll
      for (int j = 0; j < 8; ++j) {
        float a = qv[j] * kdp[16 * j] * scale;
        al[j] = a; sacc += a; s2acc += a * a;
      }
#pragma unroll
      for (int j = 0; j < 8; ++j) {
        float a = qv[j] * ksp[16 * j] * scale;
        al[8 + j] = a; sacc += a; s2acc += a * a;
      }
#pragma unroll
      for (int j = 0; j < 8; ++j) {
        float a = qv[j] * bf2f(sp[16 * j]) * scale;
        al[16 + j] = a; sacc += a; s2acc += a * a;
      }
#pragma unroll
      for (int mm = 1; mm < 16; mm <<= 1) {
        sacc += __shfl_xor(sacc, mm); s2acc += __shfl_xor(s2acc, mm);
      }
      float mean = sacc * (1.f / C3DIM);
      float rstd = rsqrtf(s2acc * (1.f / C3DIM) - mean * mean + 1e-5f);
#pragma unroll
      for (int j = 0; j < 24; ++j) {
        int f = (j >> 3) * 128 + lx + 16 * (j & 7);
        float z = (al[j] - mean) * rstd * lag[f] + lab[f];
        gate[r * 392 + f] = f2bf(1.f / (1.f + expf(-z)));
      }
    }
    __syncthreads();

    // ---- Phase 4: t -> A2p (bf16, fragment order) ----
    {
      const int c = tid & 127, hh = tid >> 7;
      const float cb0 = cb[hh * 384 + c];
      const float cb1 = cb[hh * 384 + 128 + c];
      const float cb2 = cb[hh * 384 + 256 + c];
      for (int e = 0; e < 8; ++e) {
        int edge = s * 8 + e;
        int dstn = did16[edge], srcn = sid16[edge];
        const float* pd = P12 + (size_t)dstn * 1536 + hh * 384;
        const float* ps = P12 + (size_t)srcn * 1536 + 768 + hh * 384;
        const u16* cr = &C1[edge * 1032 + 256 + hh * 384];
        const u16* gr = &gate[(hh * 8 + e) * 392];
        int m = hh * 8 + e;
        float t0 = (bf2f(cr[c])       + pd[c]       + ps[c]       + cb0) * bf2f(gr[c]);
        float t1 = (bf2f(cr[c + 128]) + pd[c + 128] + ps[c + 128] + cb1) * bf2f(gr[c + 128]);
        float t2 = (bf2f(cr[c + 256]) + pd[c + 256] + ps[c + 256] + cb2) * bf2f(gr[c + 256]);
        {
          int g = c;
          A2p[(g >> 5) * 512 + (m | (((g >> 3) & 3) << 4)) * 8 + (g & 7)] = f2bf(t0);
        }
        {
          int g = c + 128;
          A2p[(g >> 5) * 512 + (m | (((g >> 3) & 3) << 4)) * 8 + (g & 7)] = f2bf(t1);
        }
        {
          int g = c + 256;
          A2p[(g >> 5) * 512 + (m | (((g >> 3) & 3) << 4)) * 8 + (g & 7)] = f2bf(t2);
        }
      }
    }
    __syncthreads();

    // ---- GEMM2: load all A2 frags, barrier, MFMA, write C2 (aliased) ----
    {
      bf16x8 af2[12];
#pragma unroll
      for (int ks = 0; ks < 12; ++ks)
        af2[ks] = *(const bf16x8*)&A2p[ks * 512 + l * 8];
      __syncthreads();  // all reads of A2p complete before aliased C2 writes
      float bmv = 0.f;  // bias added post-MFMA per element below via bm_l[col]
      (void)bmv;
#pragma unroll
      for (int nt = 0; nt < 2; ++nt) {
        int g = w * 2 + nt;
        const u16* bb = WmT + (size_t)(g * 16 + ln) * 384 + lq * 8;
        f32x4 acc = {0.f, 0.f, 0.f, 0.f};
#pragma unroll
        for (int ks = 0; ks < 12; ++ks)
          acc = __builtin_amdgcn_mfma_f32_16x16x32_bf16(
              af2[ks], *(const bf16x8*)(bb + ks * 32), acc, 0, 0, 0);
        int col = g * 16 + ln;
        float bcol = bm_l[col];
#pragma unroll
        for (int r = 0; r < 4; ++r) C2[(lq * 4 + r) * 132 + col] = acc[r] + bcol;
      }
    }
    __syncthreads();

    // ---- LN128 + scatter ----
    {
      for (int rw = w; rw < 16; rw += 4) {
        float v0 = C2[rw * 132 + l], v1 = C2[rw * 132 + l + 64];
        float sa = v0 + v1, s2a = v0 * v0 + v1 * v1;
#pragma unroll
        for (int off2 = 32; off2 > 0; off2 >>= 1) {
          sa += __shfl_down(sa, off2); s2a += __shfl_down(s2a, off2);
        }
        sa = __shfl(sa, 0); s2a = __shfl(s2a, 0);
        float mean = sa * (1.f / CDIM);
        float rstd = rsqrtf(s2a * (1.f / CDIM) - mean * mean + 1e-5f);
        int h = rw >> 3, e = rw & 7;
        int dstn = did16[s * 8 + e];
        float o0 = (v0 - mean) * rstd * lmg[l] + lmb[l];
        float o1 = (v1 - mean) * rstd * lmg[l + 64] + lmb[l + 64];
        atomicAdd(&agg[(size_t)dstn * HCDIM + h * CDIM + l], o0);
        atomicAdd(&agg[(size_t)dstn * HCDIM + h * CDIM + l + 64], o1);
      }
    }
    __syncthreads();
  }
}

// ---------------- BN statistics ---------------------------------------------
__global__ __launch_bounds__(256) void bn_stats_kernel(
    const float* __restrict__ o, float* __restrict__ mu, float* __restrict__ rstd) {
  int c = blockIdx.x, tid = threadIdx.x;
  float s = 0.f, s2 = 0.f;
  for (int r = tid; r < N_NODES; r += 256) {
    float x = o[(size_t)r * CDIM + c];
    s += x; s2 += x * x;
  }
  __shared__ float red[8];
#pragma unroll
  for (int off = 32; off > 0; off >>= 1) {
    s += __shfl_down(s, off); s2 += __shfl_down(s2, off);
  }
  if ((tid & 63) == 0) { red[tid >> 6] = s; red[4 + (tid >> 6)] = s2; }
  __syncthreads();
  if (tid == 0) {
    float ts = red[0] + red[1] + red[2] + red[3];
    float t2 = red[4] + red[5] + red[6] + red[7];
    float m = ts * (1.f / N_NODES);
    float var = t2 * (1.f / N_NODES) - m * m;
    mu[c] = m;
    rstd[c] = rsqrtf(var + 1e-5f);
  }
}

__global__ void bn_silu_skip_kernel(
    const float* __restrict__ o, const float* __restrict__ skip,
    const float* __restrict__ mu, const float* __restrict__ rstd,
    const float* __restrict__ g, const float* __restrict__ b,
    float* __restrict__ nf) {
  int idx = blockIdx.x * blockDim.x + threadIdx.x;
  if (idx >= N_NODES * CDIM) return;
  int c = idx & (CDIM - 1);
  float x = (o[idx] - mu[c]) * rstd[c] * g[c] + b[c];
  float sig = 1.f / (1.f + expf(-x));
  nf[idx] = x * sig + skip[idx];
}

__global__ void pool_kernel(const float* __restrict__ nf, const int* __restrict__ batch,
                            float* __restrict__ psum, float* __restrict__ cnt) {
  int idx = blockIdx.x * blockDim.x + threadIdx.x;
  if (idx >= N_NODES * CDIM) return;
  int n = idx >> 7, c = idx & 127;
  int b = batch[n];
  atomicAdd(&psum[b * CDIM + c], nf[idx]);
  if (c == 0) atomicAdd(&cnt[b], 1.f);
}

__global__ void feats_kernel(const float* __restrict__ psum, const float* __restrict__ cnt,
                             const float* __restrict__ pge, const float* __restrict__ cse,
                             float* __restrict__ feats) {
  int idx = blockIdx.x * blockDim.x + threadIdx.x;
  if (idx >= N_GRAPH * 167) return;
  int b = idx / 167, j = idx - b * 167;
  float val;
  if (j < 128)      val = psum[b * CDIM + j] / fmaxf(cnt[b], 1.f);
  else if (j < 160) val = pge[b * 32 + (j - 128)];
  else              val = cse[b * 7 + (j - 160)];
  feats[idx] = val;
}

__global__ __launch_bounds__(256) void out_kernel(
    const float* __restrict__ h, const float* __restrict__ ow,
    const float* __restrict__ ob, float* __restrict__ out) {
  int b = blockIdx.x, tid = threadIdx.x;
  float s = h[b * 512 + tid] * ow[tid] + h[b * 512 + tid + 256] * ow[tid + 256];
  __shared__ float red[4];
#pragma unroll
  for (int off = 32; off > 0; off >>= 1) s += __shfl_down(s, off);
  if ((tid & 63) == 0) red[tid >> 6] = s;
  __syncthreads();
  if (tid == 0) out[b] = red[0] + red[1] + red[2] + red[3] + ob[0];
}

// ---------------- launch -----------------------------------------------------
extern "C" void kernel_launch(void* const* d_in, const int* in_sizes, int n_in,
                              void* d_out, int out_size, void* d_ws, size_t ws_size,
                              hipStream_t stream) {
  const float* x         = (const float*)d_in[0];
  const float* edge_attr = (const float*)d_in[1];
  const float* pge       = (const float*)d_in[2];
  const float* cse       = (const float*)d_in[3];
  const int*   ei        = (const int*)d_in[4];
  const int*   batch     = (const int*)d_in[5];
  const float* atom_W    = (const float*)d_in[6];
  const float* atom_b    = (const float*)d_in[7];
  const float* edge_W    = (const float*)d_in[8];
  const float* edge_b    = (const float*)d_in[9];
  const float* Wq        = (const float*)d_in[10];
  const float* bq        = (const float*)d_in[11];
  const float* Wk        = (const float*)d_in[12];
  const float* bk        = (const float*)d_in[13];
  const float* Wv        = (const float*)d_in[14];
  const float* bv        = (const float*)d_in[15];
  const float* We        = (const float*)d_in[16];
  const float* Wmu       = (const float*)d_in[17];
  const float* bmu       = (const float*)d_in[18];
  const float* Wm        = (const float*)d_in[19];
  const float* bm        = (const float*)d_in[20];
  const float* ln_m_g    = (const float*)d_in[21];
  const float* ln_m_b    = (const float*)d_in[22];
  const float* ln_a_g    = (const float*)d_in[23];
  const float* ln_a_b    = (const float*)d_in[24];
  const float* Wc        = (const float*)d_in[25];
  const float* bc        = (const float*)d_in[26];
  const float* bn_g      = (const float*)d_in[27];
  const float* bn_b      = (const float*)d_in[28];
  const float* Wskip     = (const float*)d_in[29];
  const float* bskip     = (const float*)d_in[30];
  const float* fc_W      = (const float*)d_in[31];
  const float* fc_b      = (const float*)d_in[32];
  const float* out_W     = (const float*)d_in[33];
  const float* out_b     = (const float*)d_in[34];

  float* ws = (float*)d_ws;
  size_t off = 0;
  float* nf    = ws + off; off += (size_t)N_NODES * CDIM;
  float* ef    = ws + off; off += (size_t)N_EDGES * CDIM;
  float* q     = ws + off; off += (size_t)N_NODES * HCDIM;
  float* k     = ws + off; off += (size_t)N_NODES * HCDIM;
  float* P12   = ws + off; off += (size_t)N_NODES * 1536;
  float* agg   = ws + off; off += (size_t)N_NODES * HCDIM;
  float* o     = ws + off; off += (size_t)N_NODES * CDIM;
  float* skip  = ws + off; off += (size_t)N_NODES * CDIM;
  float* WP12  = ws + off; off += (size_t)128 * 1536;
  float* WPe   = ws + off; off += (size_t)128 * 768;
  float* cbv   = ws + off; off += 768;
  float* mu    = ws + off; off += CDIM;
  float* rstd  = ws + off; off += CDIM;
  float* psum  = ws + off; off += (size_t)N_GRAPH * CDIM;
  float* cnt   = ws + off; off += N_GRAPH;
  float* feats = ws + off; off += (size_t)N_GRAPH * 167;
  float* h     = ws + off; off += (size_t)N_GRAPH * 512;
  u16* efb  = (u16*)(ws + off); off += (size_t)N_EDGES * 64;   // E*128 u16
  u16* WcT  = (u16*)(ws + off); off += 65536;                  // 1024*128 u16
  u16* WmTb = (u16*)(ws + off); off += 24576;                  // 128*384 u16

  auto gemm = [&](const float* A, const float* W, const float* bias, float* Y,
                  int M, int K, int Nn, int act) {
    dim3 grid((Nn + 63) / 64, (M + 63) / 64);
    if (act) gemm_kernel<1><<<grid, 256, 0, stream>>>(A, W, bias, Y, M, K, Nn);
    else     gemm_kernel<0><<<grid, 256, 0, stream>>>(A, W, bias, Y, M, K, Nn);
  };

  gemm(x, atom_W, atom_b, nf, N_NODES, 92, CDIM, 0);
  gemm(edge_attr, edge_W, edge_b, ef, N_EDGES, 50, CDIM, 0);
  pack_ef_kernel<<<dim3((N_EDGES * 128) / 256), dim3(256), 0, stream>>>(ef, efb);

  for (int i = 0; i < 2; ++i) {
    const float* Wv_i  = Wv + (size_t)i * CDIM * HCDIM;
    const float* We_i  = We + (size_t)i * CDIM * HCDIM;
    const float* Wmu_i = Wmu + (size_t)i * C3DIM * C3DIM;
    compose_kernel<<<dim3(6, 2, 6), 256, 0, stream>>>(Wv_i, We_i, Wmu_i, WP12, WPe);
    cb_kernel<<<dim3(3), dim3(256), 0, stream>>>(bmu + i * C3DIM, bv + i * HCDIM, Wmu_i, cbv);
    pack_wcombT_kernel<<<dim3(512), dim3(256), 0, stream>>>(We_i, WPe, WcT);
    pack_wmT_kernel<<<dim3(192), dim3(256), 0, stream>>>(Wm + (size_t)i * C3DIM * CDIM, WmTb);
    gemm(nf, Wq + (size_t)i * CDIM * HCDIM, bq + i * HCDIM, q, N_NODES, CDIM, HCDIM, 0);
    gemm(nf, Wk + (size_t)i * CDIM * HCDIM, bk + i * HCDIM, k, N_NODES, CDIM, HCDIM, 0);
    gemm(nf, WP12, nullptr, P12, N_NODES, CDIM, 1536, 0);
    hipMemsetAsync(agg, 0, (size_t)N_NODES * HCDIM * sizeof(float), stream);
    edge_kernel<<<dim3(N_EDGES / 16), dim3(256), 0, stream>>>(
        q, k, efb, ei, WcT, P12, cbv,
        ln_a_g + i * C3DIM, ln_a_b + i * C3DIM,
        WmTb, bm + i * CDIM,
        ln_m_g + i * CDIM, ln_m_b + i * CDIM, agg, N_EDGES);
    gemm(agg, Wc + (size_t)i * HCDIM * CDIM, bc + i * CDIM, o, N_NODES, HCDIM, CDIM, 0);
    bn_stats_kernel<<<dim3(CDIM), dim3(256), 0, stream>>>(o, mu, rstd);
    gemm(nf, Wskip + (size_t)i * CDIM * CDIM, bskip + i * CDIM, skip, N_NODES, CDIM, CDIM, 0);
    bn_silu_skip_kernel<<<dim3((N_NODES * CDIM + 255) / 256), dim3(256), 0, stream>>>(
        o, skip, mu, rstd, bn_g + i * CDIM, bn_b + i * CDIM, nf);
  }

  hipMemsetAsync(psum, 0, (size_t)(N_GRAPH * CDIM + N_GRAPH) * sizeof(float), stream);
  pool_kernel<<<dim3((N_NODES * CDIM + 255) / 256), dim3(256), 0, stream>>>(nf, batch, psum, cnt);
  feats_kernel<<<dim3((N_GRAPH * 167 + 255) / 256), dim3(256), 0, stream>>>(psum, cnt, pge, cse, feats);
  gemm(feats, fc_W, fc_b, h, N_GRAPH, 167, 512, 1);
  out_kernel<<<dim3(N_GRAPH), dim3(256), 0, stream>>>(h, out_W, out_b, (float*)d_out);
}